// Round 13
// baseline (139.217 us; speedup 1.0000x reference)
//
#include <hip/hip_runtime.h>

#ifndef FLT_MAX
#define FLT_MAX 3.402823466e+38f
#endif

typedef float v2f __attribute__((ext_vector_type(2)));
typedef float v4f __attribute__((ext_vector_type(4)));

__device__ __forceinline__ float sel3(int i, float a, float b, float c) {
    return i == 0 ? a : (i == 1 ? b : c);
}

__device__ __forceinline__ float sel4(int i, float a, float b, float c, float d) {
    return i == 0 ? a : (i == 1 ? b : (i == 2 ? c : d));
}

// Deterministic d2 (scalar), element-wise identical to packed pipeline below.
__device__ __forceinline__ float d2f(float ax, float ay, float az,
                                     float bx, float by, float bz) {
    const float dx = __fsub_rn(ax, bx);
    const float dy = __fsub_rn(ay, by);
    const float dz = __fsub_rn(az, bz);
    return __builtin_fmaf(dx, dx, __builtin_fmaf(dy, dy, __fmul_rn(dz, dz)));
}

__device__ __forceinline__ v2f d2p(v2f ax, v2f ay, v2f az, v2f bx, v2f by, v2f bz) {
    const v2f dx = ax - bx, dy = ay - by, dz = az - bz;
    return __builtin_elementwise_fma(dx, dx,
           __builtin_elementwise_fma(dy, dy, dz * dz));
}

// R9 kernel (best single-launch: 31.9 µs end-to-end). This round is a
// REPLICATION-SLOPE PROBE: kernel_launch fires it 5x (4 scratch + 1 real) so
// dur_us = base + 5K separates true marginal kernel cost K from fixed base.
#define SLICE 196

__global__ __launch_bounds__(256, 4) void clustgeo_scan9(
    const float* __restrict__ data,
    const int*   __restrict__ clusts,
    const int*   __restrict__ eidx,
    float*       __restrict__ out,
    int E)
{
    const int wave = threadIdx.x >> 6;
    const int lane = threadIdx.x & 63;
    const int t    = lane & 15;
    const int gsh  = lane & 48;
    const int e    = blockIdx.x * 16 + wave * 4 + (lane >> 4);
    const int ec   = e < E ? e : (E - 1);

    __shared__ __align__(16) float sx[4][4][SLICE];

    const int ca = eidx[ec];
    const int cb = eidx[E + ec];
    const int4 P1 = *reinterpret_cast<const int4*>(clusts + ca * 64 + 4 * t);
    const int4 P2 = *reinterpret_cast<const int4*>(clusts + cb * 64 + 4 * t);
    const float4 q10 = *reinterpret_cast<const float4*>(data + (size_t)P1.x * 4);
    const float4 q11 = *reinterpret_cast<const float4*>(data + (size_t)P1.y * 4);
    const float4 q12 = *reinterpret_cast<const float4*>(data + (size_t)P1.z * 4);
    const float4 q13 = *reinterpret_cast<const float4*>(data + (size_t)P1.w * 4);
    const float4 q20 = *reinterpret_cast<const float4*>(data + (size_t)P2.x * 4);
    const float4 q21 = *reinterpret_cast<const float4*>(data + (size_t)P2.y * 4);
    const float4 q22 = *reinterpret_cast<const float4*>(data + (size_t)P2.z * 4);
    const float4 q23 = *reinterpret_cast<const float4*>(data + (size_t)P2.w * 4);
    const v4f RX = {q10.y, q11.y, q12.y, q13.y};
    const v4f RY = {q10.z, q11.z, q12.z, q13.z};
    const v4f RZ = {q10.w, q11.w, q12.w, q13.w};
    const v4f CX = {q20.y, q21.y, q22.y, q23.y};
    const v4f CY = {q20.z, q21.z, q22.z, q23.z};
    const v4f CZ = {q20.w, q21.w, q22.w, q23.w};

    float* slice = &sx[wave][lane >> 4][0];
    *reinterpret_cast<v4f*>(slice + 4 * t)       = CX;
    *reinterpret_cast<v4f*>(slice + 64 + 4 * t)  = CY;
    *reinterpret_cast<v4f*>(slice + 128 + 4 * t) = CZ;
    // No barrier: each group reads only its own slice; same-wave LDS RAW is
    // ordered by compiler-inserted lgkmcnt waits (validated R3-R12).

    const v4f* SL = reinterpret_cast<const v4f*>(slice);
    v2f a0 = {FLT_MAX, FLT_MAX}, a1 = {FLT_MAX, FLT_MAX};
    v2f a2 = {FLT_MAX, FLT_MAX}, a3 = {FLT_MAX, FLT_MAX};
    #pragma unroll 2
    for (int g = 0; g < 16; ++g) {
        const v4f X = SL[g];
        const v4f Y = SL[16 + g];
        const v4f Z = SL[32 + g];
        const v2f xlo = X.xy, xhi = X.zw, ylo = Y.xy, yhi = Y.zw, zlo = Z.xy, zhi = Z.zw;
        a0 = __builtin_elementwise_min(a0, d2p((v2f){RX.x,RX.x},(v2f){RY.x,RY.x},(v2f){RZ.x,RZ.x}, xlo, ylo, zlo));
        a0 = __builtin_elementwise_min(a0, d2p((v2f){RX.x,RX.x},(v2f){RY.x,RY.x},(v2f){RZ.x,RZ.x}, xhi, yhi, zhi));
        a1 = __builtin_elementwise_min(a1, d2p((v2f){RX.y,RX.y},(v2f){RY.y,RY.y},(v2f){RZ.y,RZ.y}, xlo, ylo, zlo));
        a1 = __builtin_elementwise_min(a1, d2p((v2f){RX.y,RX.y},(v2f){RY.y,RY.y},(v2f){RZ.y,RZ.y}, xhi, yhi, zhi));
        a2 = __builtin_elementwise_min(a2, d2p((v2f){RX.z,RX.z},(v2f){RY.z,RY.z},(v2f){RZ.z,RZ.z}, xlo, ylo, zlo));
        a2 = __builtin_elementwise_min(a2, d2p((v2f){RX.z,RX.z},(v2f){RY.z,RY.z},(v2f){RZ.z,RZ.z}, xhi, yhi, zhi));
        a3 = __builtin_elementwise_min(a3, d2p((v2f){RX.w,RX.w},(v2f){RY.w,RY.w},(v2f){RZ.w,RZ.w}, xlo, ylo, zlo));
        a3 = __builtin_elementwise_min(a3, d2p((v2f){RX.w,RX.w},(v2f){RY.w,RY.w},(v2f){RZ.w,RZ.w}, xhi, yhi, zhi));
    }
    const float m0 = fminf(a0.x, a0.y);
    const float m1 = fminf(a1.x, a1.y);
    const float m2 = fminf(a2.x, a2.y);
    const float m3 = fminf(a3.x, a3.y);
    float bmn = fminf(fminf(m0, m1), fminf(m2, m3));
    #pragma unroll
    for (int off = 8; off; off >>= 1) bmn = fminf(bmn, __shfl_xor(bmn, off, 64));
    const unsigned g0 = (unsigned)(__ballot(m0 == bmn) >> gsh) & 0xFFFFu;
    const unsigned g1 = (unsigned)(__ballot(m1 == bmn) >> gsh) & 0xFFFFu;
    const unsigned g2 = (unsigned)(__ballot(m2 == bmn) >> gsh) & 0xFFFFu;
    const unsigned g3 = (unsigned)(__ballot(m3 == bmn) >> gsh) & 0xFFFFu;
    const int t1 = __builtin_ctz(g0 | g1 | g2 | g3);
    const int s1 = (g0 >> t1) & 1 ? 0 : (g1 >> t1) & 1 ? 1 : (g2 >> t1) & 1 ? 2 : 3;
    const float v1x = __shfl(sel4(s1, RX.x, RX.y, RX.z, RX.w), gsh + t1, 64);
    const float v1y = __shfl(sel4(s1, RY.x, RY.y, RY.z, RY.w), gsh + t1, 64);
    const float v1z = __shfl(sel4(s1, RZ.x, RZ.y, RZ.z, RZ.w), gsh + t1, 64);
    const float d0 = d2f(v1x, v1y, v1z, CX.x, CY.x, CZ.x);
    const float d1 = d2f(v1x, v1y, v1z, CX.y, CY.y, CZ.y);
    const float d2_ = d2f(v1x, v1y, v1z, CX.z, CY.z, CZ.z);
    const float d3 = d2f(v1x, v1y, v1z, CX.w, CY.w, CZ.w);
    const unsigned h0 = (unsigned)(__ballot(d0 == bmn) >> gsh) & 0xFFFFu;
    const unsigned h1 = (unsigned)(__ballot(d1 == bmn) >> gsh) & 0xFFFFu;
    const unsigned h2 = (unsigned)(__ballot(d2_ == bmn) >> gsh) & 0xFFFFu;
    const unsigned h3 = (unsigned)(__ballot(d3 == bmn) >> gsh) & 0xFFFFu;
    const int t2 = __builtin_ctz(h0 | h1 | h2 | h3);
    const int s2 = (h0 >> t2) & 1 ? 0 : (h1 >> t2) & 1 ? 1 : (h2 >> t2) & 1 ? 2 : 3;
    const float v2x = __shfl(sel4(s2, CX.x, CX.y, CX.z, CX.w), gsh + t2, 64);
    const float v2y = __shfl(sel4(s2, CY.x, CY.y, CY.z, CY.w), gsh + t2, 64);
    const float v2z = __shfl(sel4(s2, CZ.x, CZ.y, CZ.z, CZ.w), gsh + t2, 64);
    float dx = v1x - v2x, dy = v1y - v2y, dz = v1z - v2z;
    const float lend = sqrtf(dx * dx + dy * dy + dz * dz);
    if (lend > 0.f) { dx /= lend; dy /= lend; dz /= lend; }
    if (e < E) {
        float* orow = out + (size_t)e * 19;
        float o;
        if (t < 3)       o = sel3(t,     v1x, v1y, v1z);
        else if (t < 6)  o = sel3(t - 3, v2x, v2y, v2z);
        else if (t < 9)  o = sel3(t - 6, dx, dy, dz);
        else if (t == 9) o = lend;
        else {
            const int k = t - 10;
            o = sel3(k / 3, dx, dy, dz) * sel3(k % 3, dx, dy, dz);
        }
        orow[t] = o;
        if (t < 3) {
            const int k = t + 6;
            orow[16 + t] = sel3(k / 3, dx, dy, dz) * sel3(k % 3, dx, dy, dz);
        }
    }
}

extern "C" void kernel_launch(void* const* d_in, const int* in_sizes, int n_in,
                              void* d_out, int out_size, void* d_ws, size_t ws_size,
                              hipStream_t stream) {
    const float* data   = (const float*)d_in[0];
    const int*   clusts = (const int*)d_in[1];
    const int*   eidx   = (const int*)d_in[2];
    float*       out    = (float*)d_out;
    const int E = in_sizes[2] / 2;            // edge_index is (2, E)
    const int blocks = (E + 15) / 16;

    // Replication-slope probe: 4 scratch launches + 1 real. dur = base + 5K.
    const size_t per = (size_t)E * 19;        // floats per output image
    if (ws_size >= 4 * per * sizeof(float)) {
        float* s = (float*)d_ws;
        for (int r = 0; r < 4; ++r) {
            clustgeo_scan9<<<blocks, 256, 0, stream>>>(data, clusts, eidx, s + (size_t)r * per, E);
        }
    }
    clustgeo_scan9<<<blocks, 256, 0, stream>>>(data, clusts, eidx, out, E);
}

// Round 14
// 75.770 us; speedup vs baseline: 1.8374x; 1.8374x over previous
//
#include <hip/hip_runtime.h>

#ifndef FLT_MAX
#define FLT_MAX 3.402823466e+38f
#endif

typedef float v2f __attribute__((ext_vector_type(2)));
typedef float v4f __attribute__((ext_vector_type(4)));

__device__ __forceinline__ float sel3(int i, float a, float b, float c) {
    return i == 0 ? a : (i == 1 ? b : c);
}

__device__ __forceinline__ float sel4(int i, float a, float b, float c, float d) {
    return i == 0 ? a : (i == 1 ? b : (i == 2 ? c : d));
}

// Deterministic d2 (scalar), element-wise identical to packed pipeline below.
__device__ __forceinline__ float d2f(float ax, float ay, float az,
                                     float bx, float by, float bz) {
    const float dx = __fsub_rn(ax, bx);
    const float dy = __fsub_rn(ay, by);
    const float dz = __fsub_rn(az, bz);
    return __builtin_fmaf(dx, dx, __builtin_fmaf(dy, dy, __fmul_rn(dz, dz)));
}

__device__ __forceinline__ v2f d2p(v2f ax, v2f ay, v2f az, v2f bx, v2f by, v2f bz) {
    const v2f dx = ax - bx, dy = ay - by, dz = az - bz;
    return __builtin_elementwise_fma(dx, dx,
           __builtin_elementwise_fma(dy, dy, dz * dz));
}

// VISIBILITY ROUND: R9 scan with 3x in-dispatch replication (grid-folded).
// Reps 0-1 write scratch, rep 2 writes the real output. One ~80µs dispatch
// ranks above the harness's 40µs memset fills -> rocprof finally reports the
// scan's own VALUBusy/Occupancy/LDS_BANK_CONFLICT/FETCH.
#define SLICE 196

__global__ __launch_bounds__(256, 4) void clustgeo_scan9r(
    const float* __restrict__ data,
    const int*   __restrict__ clusts,
    const int*   __restrict__ eidx,
    float*       __restrict__ out,     // real output
    float*       __restrict__ scratch, // 2 replica images
    int E, int blocksPerRep)
{
    const int rep    = blockIdx.x / blocksPerRep;
    const int iblock = blockIdx.x % blocksPerRep;
    float* obase = (rep == 2) ? out : scratch + (size_t)rep * (size_t)E * 19;

    const int wave = threadIdx.x >> 6;
    const int lane = threadIdx.x & 63;
    const int t    = lane & 15;
    const int gsh  = lane & 48;
    const int e    = iblock * 16 + wave * 4 + (lane >> 4);
    const int ec   = e < E ? e : (E - 1);

    __shared__ __align__(16) float sx[4][4][SLICE];

    const int ca = eidx[ec];
    const int cb = eidx[E + ec];
    const int4 P1 = *reinterpret_cast<const int4*>(clusts + ca * 64 + 4 * t);
    const int4 P2 = *reinterpret_cast<const int4*>(clusts + cb * 64 + 4 * t);
    const float4 q10 = *reinterpret_cast<const float4*>(data + (size_t)P1.x * 4);
    const float4 q11 = *reinterpret_cast<const float4*>(data + (size_t)P1.y * 4);
    const float4 q12 = *reinterpret_cast<const float4*>(data + (size_t)P1.z * 4);
    const float4 q13 = *reinterpret_cast<const float4*>(data + (size_t)P1.w * 4);
    const float4 q20 = *reinterpret_cast<const float4*>(data + (size_t)P2.x * 4);
    const float4 q21 = *reinterpret_cast<const float4*>(data + (size_t)P2.y * 4);
    const float4 q22 = *reinterpret_cast<const float4*>(data + (size_t)P2.z * 4);
    const float4 q23 = *reinterpret_cast<const float4*>(data + (size_t)P2.w * 4);
    const v4f RX = {q10.y, q11.y, q12.y, q13.y};
    const v4f RY = {q10.z, q11.z, q12.z, q13.z};
    const v4f RZ = {q10.w, q11.w, q12.w, q13.w};
    const v4f CX = {q20.y, q21.y, q22.y, q23.y};
    const v4f CY = {q20.z, q21.z, q22.z, q23.z};
    const v4f CZ = {q20.w, q21.w, q22.w, q23.w};

    float* slice = &sx[wave][lane >> 4][0];
    *reinterpret_cast<v4f*>(slice + 4 * t)       = CX;
    *reinterpret_cast<v4f*>(slice + 64 + 4 * t)  = CY;
    *reinterpret_cast<v4f*>(slice + 128 + 4 * t) = CZ;
    // No barrier: each group reads only its own slice; same-wave LDS RAW is
    // ordered by compiler-inserted lgkmcnt waits (validated R3-R13).

    const v4f* SL = reinterpret_cast<const v4f*>(slice);
    v2f a0 = {FLT_MAX, FLT_MAX}, a1 = {FLT_MAX, FLT_MAX};
    v2f a2 = {FLT_MAX, FLT_MAX}, a3 = {FLT_MAX, FLT_MAX};
    #pragma unroll 2
    for (int g = 0; g < 16; ++g) {
        const v4f X = SL[g];
        const v4f Y = SL[16 + g];
        const v4f Z = SL[32 + g];
        const v2f xlo = X.xy, xhi = X.zw, ylo = Y.xy, yhi = Y.zw, zlo = Z.xy, zhi = Z.zw;
        a0 = __builtin_elementwise_min(a0, d2p((v2f){RX.x,RX.x},(v2f){RY.x,RY.x},(v2f){RZ.x,RZ.x}, xlo, ylo, zlo));
        a0 = __builtin_elementwise_min(a0, d2p((v2f){RX.x,RX.x},(v2f){RY.x,RY.x},(v2f){RZ.x,RZ.x}, xhi, yhi, zhi));
        a1 = __builtin_elementwise_min(a1, d2p((v2f){RX.y,RX.y},(v2f){RY.y,RY.y},(v2f){RZ.y,RZ.y}, xlo, ylo, zlo));
        a1 = __builtin_elementwise_min(a1, d2p((v2f){RX.y,RX.y},(v2f){RY.y,RY.y},(v2f){RZ.y,RZ.y}, xhi, yhi, zhi));
        a2 = __builtin_elementwise_min(a2, d2p((v2f){RX.z,RX.z},(v2f){RY.z,RY.z},(v2f){RZ.z,RZ.z}, xlo, ylo, zlo));
        a2 = __builtin_elementwise_min(a2, d2p((v2f){RX.z,RX.z},(v2f){RY.z,RY.z},(v2f){RZ.z,RZ.z}, xhi, yhi, zhi));
        a3 = __builtin_elementwise_min(a3, d2p((v2f){RX.w,RX.w},(v2f){RY.w,RY.w},(v2f){RZ.w,RZ.w}, xlo, ylo, zlo));
        a3 = __builtin_elementwise_min(a3, d2p((v2f){RX.w,RX.w},(v2f){RY.w,RY.w},(v2f){RZ.w,RZ.w}, xhi, yhi, zhi));
    }
    const float m0 = fminf(a0.x, a0.y);
    const float m1 = fminf(a1.x, a1.y);
    const float m2 = fminf(a2.x, a2.y);
    const float m3 = fminf(a3.x, a3.y);
    float bmn = fminf(fminf(m0, m1), fminf(m2, m3));
    #pragma unroll
    for (int off = 8; off; off >>= 1) bmn = fminf(bmn, __shfl_xor(bmn, off, 64));
    const unsigned g0 = (unsigned)(__ballot(m0 == bmn) >> gsh) & 0xFFFFu;
    const unsigned g1 = (unsigned)(__ballot(m1 == bmn) >> gsh) & 0xFFFFu;
    const unsigned g2 = (unsigned)(__ballot(m2 == bmn) >> gsh) & 0xFFFFu;
    const unsigned g3 = (unsigned)(__ballot(m3 == bmn) >> gsh) & 0xFFFFu;
    const int t1 = __builtin_ctz(g0 | g1 | g2 | g3);
    const int s1 = (g0 >> t1) & 1 ? 0 : (g1 >> t1) & 1 ? 1 : (g2 >> t1) & 1 ? 2 : 3;
    const float v1x = __shfl(sel4(s1, RX.x, RX.y, RX.z, RX.w), gsh + t1, 64);
    const float v1y = __shfl(sel4(s1, RY.x, RY.y, RY.z, RY.w), gsh + t1, 64);
    const float v1z = __shfl(sel4(s1, RZ.x, RZ.y, RZ.z, RZ.w), gsh + t1, 64);
    const float d0 = d2f(v1x, v1y, v1z, CX.x, CY.x, CZ.x);
    const float d1 = d2f(v1x, v1y, v1z, CX.y, CY.y, CZ.y);
    const float d2_ = d2f(v1x, v1y, v1z, CX.z, CY.z, CZ.z);
    const float d3 = d2f(v1x, v1y, v1z, CX.w, CY.w, CZ.w);
    const unsigned h0 = (unsigned)(__ballot(d0 == bmn) >> gsh) & 0xFFFFu;
    const unsigned h1 = (unsigned)(__ballot(d1 == bmn) >> gsh) & 0xFFFFu;
    const unsigned h2 = (unsigned)(__ballot(d2_ == bmn) >> gsh) & 0xFFFFu;
    const unsigned h3 = (unsigned)(__ballot(d3 == bmn) >> gsh) & 0xFFFFu;
    const int t2 = __builtin_ctz(h0 | h1 | h2 | h3);
    const int s2 = (h0 >> t2) & 1 ? 0 : (h1 >> t2) & 1 ? 1 : (h2 >> t2) & 1 ? 2 : 3;
    const float v2x = __shfl(sel4(s2, CX.x, CX.y, CX.z, CX.w), gsh + t2, 64);
    const float v2y = __shfl(sel4(s2, CY.x, CY.y, CY.z, CY.w), gsh + t2, 64);
    const float v2z = __shfl(sel4(s2, CZ.x, CZ.y, CZ.z, CZ.w), gsh + t2, 64);
    float dx = v1x - v2x, dy = v1y - v2y, dz = v1z - v2z;
    const float lend = sqrtf(dx * dx + dy * dy + dz * dz);
    if (lend > 0.f) { dx /= lend; dy /= lend; dz /= lend; }
    if (e < E) {
        float* orow = obase + (size_t)e * 19;
        float o;
        if (t < 3)       o = sel3(t,     v1x, v1y, v1z);
        else if (t < 6)  o = sel3(t - 3, v2x, v2y, v2z);
        else if (t < 9)  o = sel3(t - 6, dx, dy, dz);
        else if (t == 9) o = lend;
        else {
            const int k = t - 10;
            o = sel3(k / 3, dx, dy, dz) * sel3(k % 3, dx, dy, dz);
        }
        orow[t] = o;
        if (t < 3) {
            const int k = t + 6;
            orow[16 + t] = sel3(k / 3, dx, dy, dz) * sel3(k % 3, dx, dy, dz);
        }
    }
}

extern "C" void kernel_launch(void* const* d_in, const int* in_sizes, int n_in,
                              void* d_out, int out_size, void* d_ws, size_t ws_size,
                              hipStream_t stream) {
    const float* data   = (const float*)d_in[0];
    const int*   clusts = (const int*)d_in[1];
    const int*   eidx   = (const int*)d_in[2];
    float*       out    = (float*)d_out;
    const int E = in_sizes[2] / 2;            // edge_index is (2, E)
    const int blocksPerRep = (E + 15) / 16;
    const size_t per = (size_t)E * 19;

    if (ws_size >= 2 * per * sizeof(float)) {
        // 3 reps folded into one dispatch for profiler visibility.
        clustgeo_scan9r<<<3 * blocksPerRep, 256, 0, stream>>>(
            data, clusts, eidx, out, (float*)d_ws, E, blocksPerRep);
    } else {
        clustgeo_scan9r<<<blocksPerRep, 256, 0, stream>>>(
            data, clusts, eidx, out, out, E, blocksPerRep);  // rep==0 only -> writes out? (blocks < blocksPerRep*1; rep=0 writes scratch=out)
    }
}

// Round 16
// 31.598 us; speedup vs baseline: 4.4058x; 2.3979x over previous
//
#include <hip/hip_runtime.h>

#ifndef FLT_MAX
#define FLT_MAX 3.402823466e+38f
#endif

typedef float v2f __attribute__((ext_vector_type(2)));
typedef float v4f __attribute__((ext_vector_type(4)));

__device__ __forceinline__ float sel3(int i, float a, float b, float c) {
    return i == 0 ? a : (i == 1 ? b : c);
}

__device__ __forceinline__ float sel4(int i, float a, float b, float c, float d) {
    return i == 0 ? a : (i == 1 ? b : (i == 2 ? c : d));
}

// Deterministic scalar d2: sub,sub,sub,mul,fma,fma. The packed asm pipeline
// computes dx = r + (-c), which is IEEE-identical to __fsub_rn(r, c), then
// the same mul/fma chain -> phase-2 recompute is bit-identical to the scan.
__device__ __forceinline__ float d2f(float ax, float ay, float az,
                                     float bx, float by, float bz) {
    const float dx = __fsub_rn(ax, bx);
    const float dy = __fsub_rn(ay, by);
    const float dz = __fsub_rn(az, bz);
    return __builtin_fmaf(dx, dx, __builtin_fmaf(dy, dy, __fmul_rn(dz, dz)));
}

// FOUR edges per 64-lane wave (16-lane group n owns edge n); lane 16n+t owns
// rows 4t..4t+3 and cols 4t..4t+3 (R9 structure, validated). R14 counters
// proved the scan scalarized (~2670 VALU instr/wave, VALUBusy 69%): hipcc
// never forms v_pk_*_f32. This version forces VOP3P via inline asm: per g,
// one asm block of 48 packed ops covers all 16 pairs (4 rows x 4 cols),
// columns staged NEGATED in LDS so dx = pk_add(r, -c). 4 instr/pair vs 7.
#define SLICE 196

__global__ __launch_bounds__(256, 4) void clustgeo_scan_pk(
    const float* __restrict__ data,
    const int*   __restrict__ clusts,
    const int*   __restrict__ eidx,
    float*       __restrict__ out,
    int E)
{
    const int wave = threadIdx.x >> 6;
    const int lane = threadIdx.x & 63;
    const int t    = lane & 15;
    const int gsh  = lane & 48;
    const int e    = blockIdx.x * 16 + wave * 4 + (lane >> 4);
    const int ec   = e < E ? e : (E - 1);

    __shared__ __align__(16) float sx[4][4][SLICE];

    const int ca = eidx[ec];
    const int cb = eidx[E + ec];
    const int4 P1 = *reinterpret_cast<const int4*>(clusts + ca * 64 + 4 * t);
    const int4 P2 = *reinterpret_cast<const int4*>(clusts + cb * 64 + 4 * t);
    const float4 q10 = *reinterpret_cast<const float4*>(data + (size_t)P1.x * 4);
    const float4 q11 = *reinterpret_cast<const float4*>(data + (size_t)P1.y * 4);
    const float4 q12 = *reinterpret_cast<const float4*>(data + (size_t)P1.z * 4);
    const float4 q13 = *reinterpret_cast<const float4*>(data + (size_t)P1.w * 4);
    const float4 q20 = *reinterpret_cast<const float4*>(data + (size_t)P2.x * 4);
    const float4 q21 = *reinterpret_cast<const float4*>(data + (size_t)P2.y * 4);
    const float4 q22 = *reinterpret_cast<const float4*>(data + (size_t)P2.z * 4);
    const float4 q23 = *reinterpret_cast<const float4*>(data + (size_t)P2.w * 4);

    // Row broadcast pairs {r,r} (asm operands; built once).
    const v2f rx0 = {q10.y, q10.y}, rx1 = {q11.y, q11.y}, rx2 = {q12.y, q12.y}, rx3 = {q13.y, q13.y};
    const v2f ry0 = {q10.z, q10.z}, ry1 = {q11.z, q11.z}, ry2 = {q12.z, q12.z}, ry3 = {q13.z, q13.z};
    const v2f rz0 = {q10.w, q10.w}, rz1 = {q11.w, q11.w}, rz2 = {q12.w, q12.w}, rz3 = {q13.w, q13.w};

    // Stage NEGATED columns to LDS (plane p at p*64; 4-col group per lane).
    float* slice = &sx[wave][lane >> 4][0];
    *reinterpret_cast<v4f*>(slice + 4 * t)       = (v4f){-q20.y, -q21.y, -q22.y, -q23.y};
    *reinterpret_cast<v4f*>(slice + 64 + 4 * t)  = (v4f){-q20.z, -q21.z, -q22.z, -q23.z};
    *reinterpret_cast<v4f*>(slice + 128 + 4 * t) = (v4f){-q20.w, -q21.w, -q22.w, -q23.w};
    // No barrier: each group reads only its own slice; same-wave LDS RAW is
    // ordered by compiler-inserted lgkmcnt waits (validated R3-R14).

    const v4f* SL = reinterpret_cast<const v4f*>(slice);

    const v2f INF2 = {FLT_MAX, FLT_MAX};
    v2f a0l = INF2, a0h = INF2, a1l = INF2, a1h = INF2;
    v2f a2l = INF2, a2h = INF2, a3l = INF2, a3h = INF2;

    #pragma unroll 2
    for (int g = 0; g < 16; ++g) {
        const v4f X = SL[g];        // negated col x, 4 cols
        const v4f Y = SL[16 + g];
        const v4f Z = SL[32 + g];
        v2f o0, o1, o2, o3, o4, o5, o6, o7, t1, t2;
        // d2 per (row, colpair): dx=pk_add(r,-c); dy; dz; dz2=pk_mul;
        // s=pk_fma(dy,dy,dz2); d2=pk_fma(dx,dx,s).
        asm("v_pk_add_f32 %0, %10, %22\n\t"
            "v_pk_add_f32 %8, %14, %24\n\t"
            "v_pk_add_f32 %9, %18, %26\n\t"
            "v_pk_mul_f32 %9, %9, %9\n\t"
            "v_pk_fma_f32 %8, %8, %8, %9\n\t"
            "v_pk_fma_f32 %0, %0, %0, %8\n\t"

            "v_pk_add_f32 %1, %10, %23\n\t"
            "v_pk_add_f32 %8, %14, %25\n\t"
            "v_pk_add_f32 %9, %18, %27\n\t"
            "v_pk_mul_f32 %9, %9, %9\n\t"
            "v_pk_fma_f32 %8, %8, %8, %9\n\t"
            "v_pk_fma_f32 %1, %1, %1, %8\n\t"

            "v_pk_add_f32 %2, %11, %22\n\t"
            "v_pk_add_f32 %8, %15, %24\n\t"
            "v_pk_add_f32 %9, %19, %26\n\t"
            "v_pk_mul_f32 %9, %9, %9\n\t"
            "v_pk_fma_f32 %8, %8, %8, %9\n\t"
            "v_pk_fma_f32 %2, %2, %2, %8\n\t"

            "v_pk_add_f32 %3, %11, %23\n\t"
            "v_pk_add_f32 %8, %15, %25\n\t"
            "v_pk_add_f32 %9, %19, %27\n\t"
            "v_pk_mul_f32 %9, %9, %9\n\t"
            "v_pk_fma_f32 %8, %8, %8, %9\n\t"
            "v_pk_fma_f32 %3, %3, %3, %8\n\t"

            "v_pk_add_f32 %4, %12, %22\n\t"
            "v_pk_add_f32 %8, %16, %24\n\t"
            "v_pk_add_f32 %9, %20, %26\n\t"
            "v_pk_mul_f32 %9, %9, %9\n\t"
            "v_pk_fma_f32 %8, %8, %8, %9\n\t"
            "v_pk_fma_f32 %4, %4, %4, %8\n\t"

            "v_pk_add_f32 %5, %12, %23\n\t"
            "v_pk_add_f32 %8, %16, %25\n\t"
            "v_pk_add_f32 %9, %20, %27\n\t"
            "v_pk_mul_f32 %9, %9, %9\n\t"
            "v_pk_fma_f32 %8, %8, %8, %9\n\t"
            "v_pk_fma_f32 %5, %5, %5, %8\n\t"

            "v_pk_add_f32 %6, %13, %22\n\t"
            "v_pk_add_f32 %8, %17, %24\n\t"
            "v_pk_add_f32 %9, %21, %26\n\t"
            "v_pk_mul_f32 %9, %9, %9\n\t"
            "v_pk_fma_f32 %8, %8, %8, %9\n\t"
            "v_pk_fma_f32 %6, %6, %6, %8\n\t"

            "v_pk_add_f32 %7, %13, %23\n\t"
            "v_pk_add_f32 %8, %17, %25\n\t"
            "v_pk_add_f32 %9, %21, %27\n\t"
            "v_pk_mul_f32 %9, %9, %9\n\t"
            "v_pk_fma_f32 %8, %8, %8, %9\n\t"
            "v_pk_fma_f32 %7, %7, %7, %8"
            : "=&v"(o0), "=&v"(o1), "=&v"(o2), "=&v"(o3),
              "=&v"(o4), "=&v"(o5), "=&v"(o6), "=&v"(o7),
              "=&v"(t1), "=&v"(t2)
            : "v"(rx0), "v"(rx1), "v"(rx2), "v"(rx3),
              "v"(ry0), "v"(ry1), "v"(ry2), "v"(ry3),
              "v"(rz0), "v"(rz1), "v"(rz2), "v"(rz3),
              "v"(X.xy), "v"(X.zw), "v"(Y.xy), "v"(Y.zw), "v"(Z.xy), "v"(Z.zw));
        a0l = __builtin_elementwise_min(a0l, o0);
        a0h = __builtin_elementwise_min(a0h, o1);
        a1l = __builtin_elementwise_min(a1l, o2);
        a1h = __builtin_elementwise_min(a1h, o3);
        a2l = __builtin_elementwise_min(a2l, o4);
        a2h = __builtin_elementwise_min(a2h, o5);
        a3l = __builtin_elementwise_min(a3l, o6);
        a3h = __builtin_elementwise_min(a3h, o7);
    }

    const float m0 = fminf(fminf(a0l.x, a0l.y), fminf(a0h.x, a0h.y));
    const float m1 = fminf(fminf(a1l.x, a1l.y), fminf(a1h.x, a1h.y));
    const float m2 = fminf(fminf(a2l.x, a2l.y), fminf(a2h.x, a2h.y));
    const float m3 = fminf(fminf(a3l.x, a3l.y), fminf(a3h.x, a3h.y));

    float bmn = fminf(fminf(m0, m1), fminf(m2, m3));
    #pragma unroll
    for (int off = 8; off; off >>= 1) bmn = fminf(bmn, __shfl_xor(bmn, off, 64));

    // First row attaining min (row = 4t + slot: lexicographic (t, slot)).
    const unsigned g0 = (unsigned)(__ballot(m0 == bmn) >> gsh) & 0xFFFFu;
    const unsigned g1 = (unsigned)(__ballot(m1 == bmn) >> gsh) & 0xFFFFu;
    const unsigned g2 = (unsigned)(__ballot(m2 == bmn) >> gsh) & 0xFFFFu;
    const unsigned g3 = (unsigned)(__ballot(m3 == bmn) >> gsh) & 0xFFFFu;
    const int t1i = __builtin_ctz(g0 | g1 | g2 | g3);
    const int s1 = (g0 >> t1i) & 1 ? 0 : (g1 >> t1i) & 1 ? 1 : (g2 >> t1i) & 1 ? 2 : 3;

    const float v1x = __shfl(sel4(s1, q10.y, q11.y, q12.y, q13.y), gsh + t1i, 64);
    const float v1y = __shfl(sel4(s1, q10.z, q11.z, q12.z, q13.z), gsh + t1i, 64);
    const float v1z = __shfl(sel4(s1, q10.w, q11.w, q12.w, q13.w), gsh + t1i, 64);

    // Phase 2: scalar d2 for row i1 over this lane's 4 register-held cols;
    // bit-identical to the packed scan -> first match is exact numpy argmin.
    const float d0 = d2f(v1x, v1y, v1z, q20.y, q20.z, q20.w);
    const float d1 = d2f(v1x, v1y, v1z, q21.y, q21.z, q21.w);
    const float d2_ = d2f(v1x, v1y, v1z, q22.y, q22.z, q22.w);
    const float d3 = d2f(v1x, v1y, v1z, q23.y, q23.z, q23.w);
    const unsigned h0 = (unsigned)(__ballot(d0 == bmn) >> gsh) & 0xFFFFu;
    const unsigned h1 = (unsigned)(__ballot(d1 == bmn) >> gsh) & 0xFFFFu;
    const unsigned h2 = (unsigned)(__ballot(d2_ == bmn) >> gsh) & 0xFFFFu;
    const unsigned h3 = (unsigned)(__ballot(d3 == bmn) >> gsh) & 0xFFFFu;
    const int t2i = __builtin_ctz(h0 | h1 | h2 | h3);
    const int s2 = (h0 >> t2i) & 1 ? 0 : (h1 >> t2i) & 1 ? 1 : (h2 >> t2i) & 1 ? 2 : 3;

    const float v2x = __shfl(sel4(s2, q20.y, q21.y, q22.y, q23.y), gsh + t2i, 64);
    const float v2y = __shfl(sel4(s2, q20.z, q21.z, q22.z, q23.z), gsh + t2i, 64);
    const float v2z = __shfl(sel4(s2, q20.w, q21.w, q22.w, q23.w), gsh + t2i, 64);

    float dx = v1x - v2x, dy = v1y - v2y, dz = v1z - v2z;
    const float lend = sqrtf(dx * dx + dy * dy + dz * dz);
    if (lend > 0.f) {
        const float inv = 1.0f / lend;   // 1 divide + 3 muls (vs 3 divides)
        dx *= inv; dy *= inv; dz *= inv;
    }

    if (e < E) {
        float* orow = out + (size_t)e * 19;
        float o;
        if (t < 3)       o = sel3(t,     v1x, v1y, v1z);
        else if (t < 6)  o = sel3(t - 3, v2x, v2y, v2z);
        else if (t < 9)  o = sel3(t - 6, dx, dy, dz);
        else if (t == 9) o = lend;
        else {
            const int k = t - 10;
            o = sel3(k / 3, dx, dy, dz) * sel3(k % 3, dx, dy, dz);
        }
        orow[t] = o;
        if (t < 3) {
            const int k = t + 6;   // elements 16,17,18 = B[6..8]
            orow[16 + t] = sel3(k / 3, dx, dy, dz) * sel3(k % 3, dx, dy, dz);
        }
    }
}

extern "C" void kernel_launch(void* const* d_in, const int* in_sizes, int n_in,
                              void* d_out, int out_size, void* d_ws, size_t ws_size,
                              hipStream_t stream) {
    const float* data   = (const float*)d_in[0];
    const int*   clusts = (const int*)d_in[1];
    const int*   eidx   = (const int*)d_in[2];
    float*       out    = (float*)d_out;
    const int E = in_sizes[2] / 2;            // edge_index is (2, E)
    const int blocks = (E + 15) / 16;         // 16 edges per block (4 waves x 4)
    clustgeo_scan_pk<<<blocks, 256, 0, stream>>>(data, clusts, eidx, out, E);
}